// Round 5
// baseline (283.900 us; speedup 1.0000x reference)
//
#include <hip/hip_runtime.h>
#include <hip/hip_cooperative_groups.h>

namespace cg = cooperative_groups;

// Problem constants (match reference)
#define NPIX   4000000
#define NPATHS 4000
#define PPI    500
#define HH     1024
#define WW     1024
#define BB     8
#define BLK    256
#define NBLK   1024              // 4 blocks/CU x 256 CU — safe co-residency
#define NWIN   (NPIX / 64)       // 62500 full 64-elem windows (exact)
#define MAXU   16                // windows per wave: ceil(62/4)=16
#define CAP    2048
#define NXCD   8

__device__ __forceinline__ float wave_sum(float v) {
#pragma unroll
    for (int o = 32; o > 0; o >>= 1) v += __shfl_xor(v, o);
    return v;    // full sum in every lane (butterfly)
}

// ---------------- cooperative single-kernel path ----------------
__global__ __launch_bounds__(BLK, 4) void coop_kernel(
    const float* __restrict__ input, const int* __restrict__ rows,
    const int* __restrict__ cols, const int* __restrict__ seg,
    float* __restrict__ ws, float* __restrict__ out)
{
    float* sums = ws;
    float* cnts = ws + NPATHS;
    float* devs = ws + 2 * NPATHS;

    // Contiguous chunk per block; swizzle so image i stays on XCD i (L2 pin).
    const int bid   = blockIdx.x;
    const int chunk = (bid & 7) * (NBLK / 8) + (bid >> 3);
    const int wstart = (int)(((long long)chunk * NWIN) / NBLK);
    const int wend   = (int)(((long long)(chunk + 1) * NWIN) / NBLK);
    const int wid  = threadIdx.x >> 6;
    const int lane = threadIdx.x & 63;

    int   sg[MAXU];
    float vv[MAXU];
    bool  ok[MAXU];

    // Batched index loads, then up to 16 independent gathers in flight.
    {
        int rr[MAXU], cc[MAXU];
#pragma unroll
        for (int u = 0; u < MAXU; ++u) {
            const int w = wstart + wid + 4 * u;
            ok[u] = (w < wend);
            const int base = w * 64 + lane;
            if (ok[u]) { sg[u] = seg[base]; rr[u] = rows[base]; cc[u] = cols[base]; }
        }
#pragma unroll
        for (int u = 0; u < MAXU; ++u)
            if (ok[u]) vv[u] = input[(sg[u] / PPI) * (HH * WW) + rr[u] * WW + cc[u]];
    }

    // Phase 1: segmented sums + counts (sorted stream: usually 1 seg/window).
#pragma unroll
    for (int u = 0; u < MAXU; ++u) {
        if (!ok[u]) continue;                       // wave-uniform
        const int s0 = __shfl(sg[u], 0), s63 = __shfl(sg[u], 63);
        if (s0 == s63) {
            const float t = wave_sum(vv[u]);
            if (lane == 0) { atomicAdd(&sums[s0], t); atomicAdd(&cnts[s0], 64.f); }
        } else {
            bool done = false;
            while (true) {
                const unsigned long long und = __ballot(!done);
                if (!und) break;
                const int first = __ffsll((long long)und) - 1;
                const int cur   = __shfl(sg[u], first);
                const bool mine = !done && (sg[u] == cur);
                const float t   = wave_sum(mine ? vv[u] : 0.f);
                const int cnt   = __popcll(__ballot(mine));
                if (lane == first) { atomicAdd(&sums[cur], t); atomicAdd(&cnts[cur], (float)cnt); }
                done = done || mine;
            }
        }
    }

    cg::this_grid().sync();

    // Phase 2: |v - mean| from registers (no re-gather, no LDS round-trip).
#pragma unroll
    for (int u = 0; u < MAXU; ++u) {
        if (!ok[u]) continue;
        const float sm = __hip_atomic_load(&sums[sg[u]], __ATOMIC_RELAXED, __HIP_MEMORY_SCOPE_AGENT);
        const float cn = __hip_atomic_load(&cnts[sg[u]], __ATOMIC_RELAXED, __HIP_MEMORY_SCOPE_AGENT);
        const float dv = fabsf(vv[u] - sm / fmaxf(cn, 1.f));
        const int s0 = __shfl(sg[u], 0), s63 = __shfl(sg[u], 63);
        if (s0 == s63) {
            const float t = wave_sum(dv);
            if (lane == 0) atomicAdd(&devs[s0], t);
        } else {
            bool done = false;
            while (true) {
                const unsigned long long und = __ballot(!done);
                if (!und) break;
                const int first = __ffsll((long long)und) - 1;
                const int cur   = __shfl(sg[u], first);
                const bool mine = !done && (sg[u] == cur);
                const float t   = wave_sum(mine ? dv : 0.f);
                if (lane == first) atomicAdd(&devs[cur], t);
                done = done || mine;
            }
        }
    }

    cg::this_grid().sync();

    // Final: block 0 reduces the 4000 path losses to the scalar.
    if (bid == 0) {
        __shared__ float red[BLK / 64];
        float l = 0.f;
        for (int s = threadIdx.x; s < NPATHS; s += BLK) {
            const float dv = __hip_atomic_load(&devs[s], __ATOMIC_RELAXED, __HIP_MEMORY_SCOPE_AGENT);
            const float cn = __hip_atomic_load(&cnts[s], __ATOMIC_RELAXED, __HIP_MEMORY_SCOPE_AGENT);
            l += dv / fmaxf(cn, 1.f);
        }
        l = wave_sum(l);
        if ((threadIdx.x & 63) == 0) red[threadIdx.x >> 6] = l;
        __syncthreads();
        if (threadIdx.x == 0) {
            float tot = 0.f;
#pragma unroll
            for (int i = 0; i < BLK / 64; ++i) tot += red[i];
            out[0] = tot * (1.0f / (float)BB);
        }
    }
}

// ---------------- fallback path (R3, known-good 45 us) ----------------
__global__ __launch_bounds__(256) void bounds_kernel(
    const int* __restrict__ seg, int* __restrict__ bounds)
{
    const int s    = blockIdx.x * 4 + (threadIdx.x >> 6);
    const int lane = threadIdx.x & 63;
    if (s > NPATHS) return;
    if (s == NPATHS) { if (lane == 0) bounds[s] = NPIX; return; }
    int lo = 0, hi = NPIX;
    while (hi > lo) {
        const int step = (hi - lo + 63) >> 6;
        const int pos  = lo + lane * step;
        const int x    = (pos < hi) ? seg[pos] : 0x7fffffff;
        const unsigned long long m = __ballot(x < s);
        const int c = __popcll(m);
        if (c == 0) { hi = lo; break; }
        const int nlo = lo + (c - 1) * step + 1;
        const int nhi = (c < 64) ? min(hi, lo + c * step) : hi;
        lo = nlo; hi = nhi;
    }
    if (lane == 0) bounds[s] = lo;
}

__global__ __launch_bounds__(BLK) void seg_loss_kernel(
    const float* __restrict__ input, const int* __restrict__ rows,
    const int* __restrict__ cols, const int* __restrict__ bounds,
    float* __restrict__ loss)
{
    __shared__ float vals[CAP];
    __shared__ float red1[BLK / 64];
    __shared__ float red2[BLK / 64];
    __shared__ float bmean;

    const int b = blockIdx.x;
    const int s = (b & (NXCD - 1)) * PPI + (b >> 3);
    const int start = bounds[s];
    const int end   = bounds[s + 1];
    const int n     = end - start;
    const int t = threadIdx.x;
    if (n <= 0) { if (t == 0) loss[s] = 0.f; return; }

    const float* __restrict__ img = input + (s / PPI) * (HH * WW);
    const bool fits = (n <= CAP);

    const int start4 = start & ~3;
    float lsum = 0.f;
    for (int i0 = start4 + t * 4; i0 < end; i0 += BLK * 4) {
        int r[4], c[4];
        if (i0 >= start && i0 + 4 <= end) {
            const int4 rr = *(const int4*)&rows[i0];
            const int4 cc = *(const int4*)&cols[i0];
            r[0] = rr.x; r[1] = rr.y; r[2] = rr.z; r[3] = rr.w;
            c[0] = cc.x; c[1] = cc.y; c[2] = cc.z; c[3] = cc.w;
            float v[4];
#pragma unroll
            for (int u = 0; u < 4; ++u) v[u] = img[r[u] * WW + c[u]];
#pragma unroll
            for (int u = 0; u < 4; ++u) {
                if (fits) vals[i0 - start + u] = v[u];
                lsum += v[u];
            }
        } else {
#pragma unroll
            for (int u = 0; u < 4; ++u) {
                const int j = i0 + u;
                if (j >= start && j < end) {
                    const float v = img[rows[j] * WW + cols[j]];
                    if (fits) vals[j - start] = v;
                    lsum += v;
                }
            }
        }
    }
    float wsum = wave_sum(lsum);
    if ((t & 63) == 0) red1[t >> 6] = wsum;
    __syncthreads();
    if (t == 0) {
        float tot = 0.f;
#pragma unroll
        for (int i = 0; i < BLK / 64; ++i) tot += red1[i];
        bmean = tot / (float)n;
    }
    __syncthreads();
    const float mean = bmean;

    float ldev = 0.f;
    if (fits) {
        for (int li = t; li < n; li += BLK) ldev += fabsf(vals[li] - mean);
    } else {
        for (int j = start + t; j < end; j += BLK)
            ldev += fabsf(img[rows[j] * WW + cols[j]] - mean);
    }
    float wdev = wave_sum(ldev);
    if ((t & 63) == 0) red2[t >> 6] = wdev;
    __syncthreads();
    if (t == 0) {
        float tot = 0.f;
#pragma unroll
        for (int i = 0; i < BLK / 64; ++i) tot += red2[i];
        loss[s] = tot / (float)n;
    }
}

__global__ __launch_bounds__(BLK) void final_reduce(
    const float* __restrict__ loss, float* __restrict__ out)
{
    __shared__ float red[BLK / 64];
    float l = 0.f;
    for (int i = threadIdx.x; i < NPATHS; i += BLK) l += loss[i];
    float w = wave_sum(l);
    if ((threadIdx.x & 63) == 0) red[threadIdx.x >> 6] = w;
    __syncthreads();
    if (threadIdx.x == 0) {
        float tot = 0.f;
#pragma unroll
        for (int i = 0; i < BLK / 64; ++i) tot += red[i];
        out[0] = tot * (1.0f / (float)BB);
    }
}

extern "C" void kernel_launch(void* const* d_in, const int* in_sizes, int n_in,
                              void* d_out, int out_size, void* d_ws, size_t ws_size,
                              hipStream_t stream) {
    const float* input = (const float*)d_in[0];
    const int* rows    = (const int*)d_in[1];
    const int* cols    = (const int*)d_in[2];
    const int* segp    = (const int*)d_in[3];
    float* out         = (float*)d_out;
    float* ws          = (float*)d_ws;   // sums[4000] | cnts[4000] | devs[4000]

    hipMemsetAsync(d_ws, 0, 3 * NPATHS * sizeof(float), stream);

    void* args[] = {(void*)&input, (void*)&rows, (void*)&cols,
                    (void*)&segp, (void*)&ws, (void*)&out};
    hipError_t e = hipLaunchCooperativeKernel((void*)coop_kernel, dim3(NBLK),
                                              dim3(BLK), args, 0, stream);
    if (e != hipSuccess) {
        // Fallback: proven 3-kernel path. Separate ws region from coop's.
        int* bounds = (int*)(ws + 3 * NPATHS);              // NPATHS+1 ints
        float* loss = ws + 3 * NPATHS + NPATHS + 1;         // NPATHS floats
        bounds_kernel<<<(NPATHS + 1 + 3) / 4, 256, 0, stream>>>(segp, bounds);
        seg_loss_kernel<<<NPATHS, BLK, 0, stream>>>(input, rows, cols, bounds, loss);
        final_reduce<<<1, BLK, 0, stream>>>(loss, out);
    }
}

// Round 6
// 41.637 us; speedup vs baseline: 6.8184x; 6.8184x over previous
//
#include <hip/hip_runtime.h>

// Problem constants (match reference)
#define NPIX   4000000
#define NPATHS 4000
#define PPI    500      // paths per image
#define HH     1024
#define WW     1024
#define BB     8
#define BLK    256
#define NU     8        // values per thread in registers (covers n <= 2048)
#define NXCD   8

__device__ __forceinline__ float wave_sum(float v) {
#pragma unroll
    for (int o = 32; o > 0; o >>= 1) v += __shfl_xor(v, o);
    return v;
}

// One WAVE per segment boundary: 64-ary cooperative lower_bound.
__global__ __launch_bounds__(256) void bounds_kernel(
    const int* __restrict__ seg, int* __restrict__ bounds)
{
    const int s    = blockIdx.x * 4 + (threadIdx.x >> 6);
    const int lane = threadIdx.x & 63;
    if (s > NPATHS) return;
    if (s == NPATHS) { if (lane == 0) bounds[s] = NPIX; return; }
    int lo = 0, hi = NPIX;
    while (hi > lo) {
        const int step = (hi - lo + 63) >> 6;
        const int pos  = lo + lane * step;
        const int x    = (pos < hi) ? seg[pos] : 0x7fffffff;
        const unsigned long long m = __ballot(x < s);
        const int c = __popcll(m);
        if (c == 0) { hi = lo; break; }
        const int nlo = lo + (c - 1) * step + 1;
        const int nhi = (c < 64) ? min(hi, lo + c * step) : hi;
        lo = nlo; hi = nhi;
    }
    if (lane == 0) bounds[s] = lo;
}

// One block per segment, values held in REGISTERS (no LDS cache).
// 8 gathers + 16 index loads in flight per thread; XCD-pinned images.
__global__ __launch_bounds__(BLK) void seg_loss_kernel(
    const float* __restrict__ input, const int* __restrict__ rows,
    const int* __restrict__ cols, const int* __restrict__ bounds,
    float* __restrict__ loss)
{
    __shared__ float red1[BLK / 64];
    __shared__ float red2[BLK / 64];
    __shared__ float bmean;

    const int b = blockIdx.x;
    const int s = (b & (NXCD - 1)) * PPI + (b >> 3);   // image i -> XCD i
    const int start = bounds[s];
    const int end   = bounds[s + 1];
    const int n     = end - start;
    const int t = threadIdx.x;
    if (n <= 0) { if (t == 0) loss[s] = 0.f; return; }

    const float* __restrict__ img = input + (s / PPI) * (HH * WW);
    const bool fits = (n <= NU * BLK);

    float v[NU];
    float lsum = 0.f;

    if (fits) {
        int r[NU], c[NU];
        bool ok[NU];
#pragma unroll
        for (int u = 0; u < NU; ++u) {               // 16 coalesced index loads
            const int j = start + u * BLK + t;
            ok[u] = (j < end);
            if (ok[u]) { r[u] = rows[j]; c[u] = cols[j]; }
        }
#pragma unroll
        for (int u = 0; u < NU; ++u)                 // 8 gathers in flight
            if (ok[u]) v[u] = img[r[u] * WW + c[u]];
#pragma unroll
        for (int u = 0; u < NU; ++u)
            if (ok[u]) lsum += v[u];
    } else {
        for (int j = start + t; j < end; j += BLK)
            lsum += img[rows[j] * WW + cols[j]];
    }

    float w = wave_sum(lsum);
    if ((t & 63) == 0) red1[t >> 6] = w;
    __syncthreads();
    if (t == 0) {
        float tot = 0.f;
#pragma unroll
        for (int i = 0; i < BLK / 64; ++i) tot += red1[i];
        bmean = tot / (float)n;
    }
    __syncthreads();
    const float mean = bmean;

    // Pass 2: pure register math (re-gather only in the never-hit oversize case)
    float ldev = 0.f;
    if (fits) {
#pragma unroll
        for (int u = 0; u < NU; ++u) {
            const int j = start + u * BLK + t;
            if (j < end) ldev += fabsf(v[u] - mean);
        }
    } else {
        for (int j = start + t; j < end; j += BLK)
            ldev += fabsf(img[rows[j] * WW + cols[j]] - mean);
    }
    float w2 = wave_sum(ldev);
    if ((t & 63) == 0) red2[t >> 6] = w2;
    __syncthreads();
    if (t == 0) {
        float tot = 0.f;
#pragma unroll
        for (int i = 0; i < BLK / 64; ++i) tot += red2[i];
        loss[s] = tot / (float)n;
    }
}

// Single block: sum the 4000 per-segment losses, divide by B, write scalar.
__global__ __launch_bounds__(BLK) void final_reduce(
    const float* __restrict__ loss, float* __restrict__ out)
{
    __shared__ float red[BLK / 64];
    float l = 0.f;
    for (int i = threadIdx.x; i < NPATHS; i += BLK) l += loss[i];
    float w = wave_sum(l);
    if ((threadIdx.x & 63) == 0) red[threadIdx.x >> 6] = w;
    __syncthreads();
    if (threadIdx.x == 0) {
        float tot = 0.f;
#pragma unroll
        for (int i = 0; i < BLK / 64; ++i) tot += red[i];
        out[0] = tot * (1.0f / (float)BB);
    }
}

extern "C" void kernel_launch(void* const* d_in, const int* in_sizes, int n_in,
                              void* d_out, int out_size, void* d_ws, size_t ws_size,
                              hipStream_t stream) {
    const float* input = (const float*)d_in[0];
    const int* rows    = (const int*)d_in[1];
    const int* cols    = (const int*)d_in[2];
    const int* segs    = (const int*)d_in[3];
    float* out         = (float*)d_out;
    int* bounds        = (int*)d_ws;                        // NPATHS+1 ints
    float* loss        = (float*)d_ws + (NPATHS + 1);       // NPATHS floats

    bounds_kernel<<<(NPATHS + 1 + 3) / 4, 256, 0, stream>>>(segs, bounds);
    seg_loss_kernel<<<NPATHS, BLK, 0, stream>>>(input, rows, cols, bounds, loss);
    final_reduce<<<1, BLK, 0, stream>>>(loss, out);
}